// Round 12
// baseline (143515.503 us; speedup 1.0000x reference)
//
#include <hip/hip_runtime.h>

#define VV    32000
#define EE    256
#define RSZ   1024
#define BB    64
#define TT    2048
#define NGRP  3
#define EPSLN 1e-5f

#define NBLK_PER_GRP 64
#define NBLK  (NBLK_PER_GRP * NGRP)   // 192 blocks
#define NTHR  512                     // 8 waves = 16 k-groups x 32 threads
#define SLAB  (BB * RSZ)

#define BAR_OFF (NGRP * 2 * SLAB)     // floats offset of barrier words in d_ws
#define EMB_OFF (BAR_OFF + 1024)      // floats offset of embed staging slab

// one k-step (4 k's): 8 rows x 4 cols = 128 FMAs per 4 weight ds_read_b128
__device__ __forceinline__ void fma_step8x4(const float4 (&b)[8], const float* wrow,
                                            float (&acc)[8][4]) {
#pragma unroll
    for (int j = 0; j < 4; ++j) {
        const float4 w = *reinterpret_cast<const float4*>(wrow + j * 16);
#pragma unroll
        for (int r = 0; r < 8; ++r) {
            const float a = reinterpret_cast<const float*>(&b[r])[j];
            acc[r][0] = fmaf(a, w.x, acc[r][0]);
            acc[r][1] = fmaf(a, w.y, acc[r][1]);
            acc[r][2] = fmaf(a, w.z, acc[r][2]);
            acc[r][3] = fmaf(a, w.w, acc[r][3]);
        }
    }
}

__device__ __forceinline__ void ld8(float4 (&b)[8], const float* const (&p)[8],
                                    int off) {
#pragma unroll
    for (int r = 0; r < 8; ++r)
        b[r] = *reinterpret_cast<const float4*>(p[r] + off);
}

// NSTEPS (even) k-steps; named A/B double-buffer, rolled 2-step loop
template<int NSTEPS>
__device__ __forceinline__ void dot8(const float* const (&p)[8],
                                     const float* w, float (&acc)[8][4]) {
    float4 A[8], B[8];
    ld8(A, p, 0);
    ld8(B, p, 4);
    for (int j = 0; j < NSTEPS - 2; j += 2) {
        fma_step8x4(A, w + j * 64, acc);
        ld8(A, p, (j + 2) * 4);
        fma_step8x4(B, w + (j + 1) * 64, acc);
        ld8(B, p, (j + 3) * 4);
    }
    fma_step8x4(A, w + (NSTEPS - 2) * 64, acc);
    fma_step8x4(B, w + (NSTEPS - 1) * 64, acc);
}

__global__ __launch_bounds__(NTHR, 1)
void reservoir_main(const int*   __restrict__ x,        // [B,T]
                    const float* __restrict__ embed_w,  // [V,E]
                    const float* __restrict__ Win0,
                    const float* __restrict__ Win1,
                    const float* __restrict__ Win2,
                    const float* __restrict__ Rm0,
                    const float* __restrict__ Rm1,
                    const float* __restrict__ Rm2,
                    const float* __restrict__ ln_w,
                    const float* __restrict__ ln_b,
                    float*       __restrict__ states,
                    unsigned*    __restrict__ bar,
                    float*       __restrict__ estage,   // [2][64][256]
                    float*       __restrict__ out)
{
    const int blk   = blockIdx.x;
    const int grp   = blk >> 6;              // layer
    const int gb    = blk & 63;
    const int c0    = gb << 4;               // 16-col slice
    const int tid   = threadIdx.x;
    const int kg    = tid >> 5;              // 0..15 (k-groups of 32 threads)
    const int idx   = tid & 31;
    const int rbase = (idx >> 2) << 3;       // 8 rows/thread: 0,8,...,56
    const int cg4   = (idx & 3) << 2;        // col quad
    const int lane  = tid & 63;
    const int g2    = tid >> 6;              // wave id = post-shuffle group 0..7

    const float* Wl  = (grp == 0) ? Win0 : ((grp == 1) ? Win1 : Win2);
    const float* Rl  = (grp == 0) ? Rm0  : ((grp == 1) ? Rm1  : Rm2);
    const int    Kw  = (grp == 0) ? EE : RSZ;
    const int    KwS = Kw >> 4;              // per-kg input k-slice (16 or 64)

    __shared__ float wlds[2048 * 16];        // 128 KB weight slab [k][16]
    __shared__ float pbuf[8][32][20];        // 20 KB partials (padded+swizzled)

    for (int i = tid; i < RSZ * 16; i += NTHR) {
        const int k = i >> 4, c = i & 15;
        wlds[i] = Rl[(size_t)k * RSZ + c0 + c];
    }
    for (int i = tid; i < Kw * 16; i += NTHR) {
        const int k = i >> 4, c = i & 15;
        wlds[RSZ * 16 + i] = Wl[(size_t)k * RSZ + c0 + c];
    }
    __syncthreads();

    // hierarchical barrier storage: 8 leaf lines + root + epoch
    unsigned* leaf  = bar;
    unsigned* root  = bar + 128;
    unsigned* epoch = bar + 160;

    float* const sl = states + (size_t)grp * 2 * SLAB;
    const float* const wRb = wlds + (kg << 6) * 16 + cg4;            // R: k-slice 64
    const float* const wWb = wlds + (RSZ + kg * KwS) * 16 + cg4;

    for (int tick = -1; tick < TT + NGRP - 1; ++tick) {
        const int t = tick - grp;            // uniform per block
        if (0 <= t && t < TT) {
            const float* sprev = sl + (size_t)((t + 1) & 1) * SLAB;

            float acc[8][4];
#pragma unroll
            for (int r = 0; r < 8; ++r)
#pragma unroll
                for (int c = 0; c < 4; ++c) acc[r][c] = 0.f;

            {   // recurrent: s_prev @ R_l, k in [kg*64, kg*64+64) -> 16 ksteps
                const float* aR[8];
#pragma unroll
                for (int r = 0; r < 8; ++r)
                    aR[r] = sprev + (size_t)(rbase + r) * RSZ + (kg << 6);
                dot8<16>(aR, wRb, acc);
            }
            {   // input: cur @ W_l
                const float* aW[8];
                if (grp == 0) {              // staged embed slab: [64][256] linear
                    const float* eb = estage + (size_t)(t & 1) * (BB * EE);
#pragma unroll
                    for (int r = 0; r < 8; ++r)
                        aW[r] = eb + (rbase + r) * EE + kg * KwS;
                    dot8<4>(aW, wWb, acc);
                } else {
                    const float* cb = states + ((size_t)(grp - 1) * 2 + (t & 1)) * SLAB;
#pragma unroll
                    for (int r = 0; r < 8; ++r)
                        aW[r] = cb + (size_t)(rbase + r) * RSZ + kg * KwS;
                    dot8<16>(aW, wWb, acc);
                }
            }

            // ---- wave-level pre-reduce: fold kg pairs (16 -> 8 groups) ----
#pragma unroll
            for (int r = 0; r < 8; ++r)
#pragma unroll
                for (int c = 0; c < 4; ++c)
                    acc[r][c] += __shfl_down(acc[r][c], 32, 64);

            // ---- reduce over 8 groups, 2 row-half phases ----
            float* sout = sl + (size_t)(t & 1) * SLAB;
#pragma unroll
            for (int p = 0; p < 2; ++p) {
                if (lane < 32 && (lane >> 4) == p) {
#pragma unroll
                    for (int r = 0; r < 8; ++r) {
                        const int lr = (rbase + r) & 31;
                        *reinterpret_cast<float4*>(
                            &pbuf[g2][lr][cg4 ^ ((lr & 3) << 2)])
                            = make_float4(acc[r][0], acc[r][1], acc[r][2], acc[r][3]);
                    }
                }
                __syncthreads();
                {
                    const int rl = tid >> 4, col = tid & 15;   // 512 thr = 32x16
                    const int cw = ((col & 12) ^ ((rl & 3) << 2)) | (col & 3);
                    float s = 0.f;
#pragma unroll
                    for (int g = 0; g < 8; ++g) s += pbuf[g][rl][cw];
                    sout[(size_t)(32 * p + rl) * RSZ + c0 + col] = tanhf(s);
                }
                __syncthreads();
            }
        }

        // ---- stage next tick's embed rows (layer 0; overlapped, pre-barrier) ----
        if (grp == 0 && tick + 1 < TT) {
            if (tid < 64) {
                const int tok = x[gb * TT + (tick + 1)];
                const float4 v = *reinterpret_cast<const float4*>(
                    embed_w + (size_t)tok * EE + (tid << 2));
                *reinterpret_cast<float4*>(
                    estage + (size_t)((tick + 1) & 1) * (BB * EE) + gb * EE + (tid << 2)) = v;
            }
        }

        // ---- hierarchical device barrier (monotonic epoch) ----
        __syncthreads();
        if (tid == 0) {
            __threadfence();                 // release
            const unsigned target = (unsigned)(tick + 2);
            unsigned prev = atomicAdd(&leaf[(blk & 7) << 4], 1u);
            if (prev == 24u * target - 1u) { // last of this leaf
                prev = atomicAdd(root, 1u);
                if (prev == 8u * target - 1u)
                    __hip_atomic_store(epoch, target, __ATOMIC_RELEASE,
                                       __HIP_MEMORY_SCOPE_AGENT);
            }
            while (__hip_atomic_load(epoch, __ATOMIC_RELAXED,
                                     __HIP_MEMORY_SCOPE_AGENT) < target)
                __builtin_amdgcn_s_sleep(2);
            __threadfence();                 // acquire
        }
        __syncthreads();
    }

    // ---- LayerNorm over h = s_2(T-1) (slot 1), blocks 0..63, 2 elems/thread ----
    if (blk < BB) {
        const float* h = states + ((size_t)2 * 2 + 1) * SLAB + (size_t)blk * RSZ;
        float* red = &pbuf[0][0][0];

        const float hv0 = h[tid];
        const float hv1 = h[tid + 512];
        float v = hv0 + hv1;
#pragma unroll
        for (int o = 32; o > 0; o >>= 1) v += __shfl_down(v, o, 64);
        if ((tid & 63) == 0) red[tid >> 6] = v;
        __syncthreads();
        if (tid == 0) {
            float s = 0.f;
#pragma unroll
            for (int i = 0; i < 8; ++i) s += red[i];
            red[20] = s / (float)RSZ;
        }
        __syncthreads();
        const float mu = red[20];
        const float d0 = hv0 - mu, d1 = hv1 - mu;
        v = d0 * d0 + d1 * d1;
#pragma unroll
        for (int o = 32; o > 0; o >>= 1) v += __shfl_down(v, o, 64);
        __syncthreads();
        if ((tid & 63) == 0) red[tid >> 6] = v;
        __syncthreads();
        if (tid == 0) {
            float s = 0.f;
#pragma unroll
            for (int i = 0; i < 8; ++i) s += red[i];
            red[21] = rsqrtf(s / (float)RSZ + EPSLN);
        }
        __syncthreads();
        const float inv = red[21];
        out[blk * RSZ + tid]       = d0 * inv * ln_w[tid]       + ln_b[tid];
        out[blk * RSZ + tid + 512] = d1 * inv * ln_w[tid + 512] + ln_b[tid + 512];
    }
}

extern "C" void kernel_launch(void* const* d_in, const int* in_sizes, int n_in,
                              void* d_out, int out_size, void* d_ws, size_t ws_size,
                              hipStream_t stream) {
    const int*   x       = (const int*)  d_in[0];
    const float* embed_w = (const float*)d_in[1];
    const float* Win0    = (const float*)d_in[2];
    const float* Win1    = (const float*)d_in[3];
    const float* Win2    = (const float*)d_in[4];
    const float* Rm0     = (const float*)d_in[5];
    const float* Rm1     = (const float*)d_in[6];
    const float* Rm2     = (const float*)d_in[7];
    const float* ln_w    = (const float*)d_in[8];
    const float* ln_b    = (const float*)d_in[9];
    float*       out     = (float*)d_out;
    float*       states  = (float*)d_ws;
    unsigned*    bar     = (unsigned*)((float*)d_ws + BAR_OFF);
    float*       estage  = (float*)d_ws + EMB_OFF;

    // zero states (s(-1)=0) AND barrier counters (estage fully written each call)
    hipMemsetAsync(d_ws, 0, (size_t)BAR_OFF * sizeof(float) + 4096, stream);

    void* args[] = {
        (void*)&x, (void*)&embed_w,
        (void*)&Win0, (void*)&Win1, (void*)&Win2,
        (void*)&Rm0, (void*)&Rm1, (void*)&Rm2,
        (void*)&ln_w, (void*)&ln_b,
        (void*)&states, (void*)&bar, (void*)&estage, (void*)&out
    };
    hipLaunchCooperativeKernel(reinterpret_cast<void*>(reservoir_main),
                               dim3(NBLK), dim3(NTHR), args, 0, stream);
}

// Round 13
// 91178.693 us; speedup vs baseline: 1.5740x; 1.5740x over previous
//
#include <hip/hip_runtime.h>

#define VV    32000
#define EE    256
#define RSZ   1024
#define BB    64
#define TT    2048
#define NGRP  3
#define EPSLN 1e-5f

#define NBLK_PER_GRP 64
#define NBLK  (NBLK_PER_GRP * NGRP)   // 192 blocks
#define NTHR  512                     // 8 waves = 16 k-groups x 32 threads
#define SLAB  (BB * RSZ)

#define BAR_OFF (NGRP * 2 * SLAB)     // floats offset of barrier words in d_ws

// one k-step (4 k's): 8 rows x 4 cols = 128 FMAs per 4 weight ds_read_b128
__device__ __forceinline__ void fma_step8x4(const float4 (&b)[8], const float* wrow,
                                            float (&acc)[8][4]) {
#pragma unroll
    for (int j = 0; j < 4; ++j) {
        const float4 w = *reinterpret_cast<const float4*>(wrow + j * 16);
#pragma unroll
        for (int r = 0; r < 8; ++r) {
            const float a = reinterpret_cast<const float*>(&b[r])[j];
            acc[r][0] = fmaf(a, w.x, acc[r][0]);
            acc[r][1] = fmaf(a, w.y, acc[r][1]);
            acc[r][2] = fmaf(a, w.z, acc[r][2]);
            acc[r][3] = fmaf(a, w.w, acc[r][3]);
        }
    }
}

// NSTEPS (multiple of 4) k-steps; depth-4 NAMED ring R0..R3 (128 VGPRs),
// rolled 4-step main loop, advancing pointers, all buffer indices static.
template<int NSTEPS>
__device__ __forceinline__ void dot8(const float* const (&p0)[8],
                                     const float* w, float (&acc)[8][4]) {
    const float* p[8];
#pragma unroll
    for (int r = 0; r < 8; ++r) p[r] = p0[r];

    float4 R0[8], R1[8], R2[8], R3[8];
#pragma unroll
    for (int r = 0; r < 8; ++r) R0[r] = *reinterpret_cast<const float4*>(p[r] + 0);
#pragma unroll
    for (int r = 0; r < 8; ++r) R1[r] = *reinterpret_cast<const float4*>(p[r] + 4);
#pragma unroll
    for (int r = 0; r < 8; ++r) R2[r] = *reinterpret_cast<const float4*>(p[r] + 8);
#pragma unroll
    for (int r = 0; r < 8; ++r) R3[r] = *reinterpret_cast<const float4*>(p[r] + 12);

    int j = 0;
    for (; j + 8 <= NSTEPS; j += 4) {        // compute 4 ksteps, prefetch next 4
#pragma unroll
        for (int r = 0; r < 8; ++r) p[r] += 16;
        fma_step8x4(R0, w + (j + 0) * 64, acc);
#pragma unroll
        for (int r = 0; r < 8; ++r) R0[r] = *reinterpret_cast<const float4*>(p[r] + 0);
        fma_step8x4(R1, w + (j + 1) * 64, acc);
#pragma unroll
        for (int r = 0; r < 8; ++r) R1[r] = *reinterpret_cast<const float4*>(p[r] + 4);
        fma_step8x4(R2, w + (j + 2) * 64, acc);
#pragma unroll
        for (int r = 0; r < 8; ++r) R2[r] = *reinterpret_cast<const float4*>(p[r] + 8);
        fma_step8x4(R3, w + (j + 3) * 64, acc);
#pragma unroll
        for (int r = 0; r < 8; ++r) R3[r] = *reinterpret_cast<const float4*>(p[r] + 12);
    }
    fma_step8x4(R0, w + (j + 0) * 64, acc);  // drain last 4 ksteps
    fma_step8x4(R1, w + (j + 1) * 64, acc);
    fma_step8x4(R2, w + (j + 2) * 64, acc);
    fma_step8x4(R3, w + (j + 3) * 64, acc);
}

__global__ __launch_bounds__(NTHR, 1)
void reservoir_main(const int*   __restrict__ x,        // [B,T]
                    const float* __restrict__ embed_w,  // [V,E]
                    const float* __restrict__ Win0,
                    const float* __restrict__ Win1,
                    const float* __restrict__ Win2,
                    const float* __restrict__ Rm0,
                    const float* __restrict__ Rm1,
                    const float* __restrict__ Rm2,
                    const float* __restrict__ ln_w,
                    const float* __restrict__ ln_b,
                    float*       __restrict__ states,
                    unsigned*    __restrict__ bar,
                    float*       __restrict__ out)
{
    const int blk   = blockIdx.x;
    const int grp   = blk >> 6;              // layer
    const int gb    = blk & 63;
    const int c0    = gb << 4;               // 16-col slice
    const int tid   = threadIdx.x;
    const int kg    = tid >> 5;              // 0..15 (k-groups of 32 threads)
    const int idx   = tid & 31;
    const int rbase = (idx >> 2) << 3;       // 8 rows/thread: 0,8,...,56
    const int cg4   = (idx & 3) << 2;        // col quad
    const int ph    = rbase >> 4;            // reduce write-phase 0..3

    const float* Wl  = (grp == 0) ? Win0 : ((grp == 1) ? Win1 : Win2);
    const float* Rl  = (grp == 0) ? Rm0  : ((grp == 1) ? Rm1  : Rm2);
    const int    Kw  = (grp == 0) ? EE : RSZ;
    const int    KwS = Kw >> 4;              // per-kg input k-slice (16 or 64)

    __shared__ float wlds[2048 * 16];        // 128 KB weight slab [k][16]
    __shared__ float pbuf[16][16][20];       // 20 KB partials (padded+swizzled)

    for (int i = tid; i < RSZ * 16; i += NTHR) {
        const int k = i >> 4, c = i & 15;
        wlds[i] = Rl[(size_t)k * RSZ + c0 + c];
    }
    for (int i = tid; i < Kw * 16; i += NTHR) {
        const int k = i >> 4, c = i & 15;
        wlds[RSZ * 16 + i] = Wl[(size_t)k * RSZ + c0 + c];
    }
    __syncthreads();

    // hierarchical barrier storage: 8 leaf lines + root + epoch
    unsigned* leaf  = bar;
    unsigned* root  = bar + 128;
    unsigned* epoch = bar + 160;

    float* const sl = states + (size_t)grp * 2 * SLAB;
    const float* const wRb = wlds + (kg << 6) * 16 + cg4;            // R: k-slice 64
    const float* const wWb = wlds + (RSZ + kg * KwS) * 16 + cg4;

    int xidx[8];
    if (grp == 0) {
#pragma unroll
        for (int r = 0; r < 8; ++r) xidx[r] = x[(rbase + r) * TT + 0];
    }

    for (int tick = 0; tick < TT + NGRP - 1; ++tick) {
        const int t = tick - grp;            // uniform per block
        if (0 <= t && t < TT) {
            const float* sprev = sl + (size_t)((t + 1) & 1) * SLAB;

            float acc[8][4];
#pragma unroll
            for (int r = 0; r < 8; ++r)
#pragma unroll
                for (int c = 0; c < 4; ++c) acc[r][c] = 0.f;

            {   // recurrent: s_prev @ R_l, k in [kg*64, kg*64+64) -> 16 ksteps
                const float* aR[8];
#pragma unroll
                for (int r = 0; r < 8; ++r)
                    aR[r] = sprev + (size_t)(rbase + r) * RSZ + (kg << 6);
                dot8<16>(aR, wRb, acc);
            }
            {   // input: cur @ W_l, k in [kg*KwS, +KwS) -> 4 or 16 ksteps
                const float* aW[8];
                if (grp == 0) {
#pragma unroll
                    for (int r = 0; r < 8; ++r)
                        aW[r] = embed_w + (size_t)xidx[r] * EE + kg * KwS;
                    dot8<4>(aW, wWb, acc);
                } else {
                    const float* cb = states + ((size_t)(grp - 1) * 2 + (t & 1)) * SLAB;
#pragma unroll
                    for (int r = 0; r < 8; ++r)
                        aW[r] = cb + (size_t)(rbase + r) * RSZ + kg * KwS;
                    dot8<16>(aW, wWb, acc);
                }
            }

            // prefetch next tick's token indices (layer 0 only)
            if (grp == 0 && t + 1 < TT) {
#pragma unroll
                for (int r = 0; r < 8; ++r) xidx[r] = x[(rbase + r) * TT + t + 1];
            }

            // ---- reduce over 16 k-groups, 4 row-quarter phases ----
            float* sout = sl + (size_t)(t & 1) * SLAB;
#pragma unroll
            for (int p = 0; p < 4; ++p) {
                if (ph == p) {
#pragma unroll
                    for (int r = 0; r < 8; ++r) {
                        const int lr = (rbase + r) & 15;
                        *reinterpret_cast<float4*>(
                            &pbuf[kg][lr][cg4 ^ ((lr & 3) << 2)])
                            = make_float4(acc[r][0], acc[r][1], acc[r][2], acc[r][3]);
                    }
                }
                __syncthreads();
                if (tid < 256) {
                    const int rl = tid >> 4, col = tid & 15;
                    const int cw = ((col & 12) ^ ((rl & 3) << 2)) | (col & 3);
                    float s = 0.f;
#pragma unroll
                    for (int g = 0; g < 16; ++g) s += pbuf[g][rl][cw];
                    sout[(size_t)(16 * p + rl) * RSZ + c0 + col] = tanhf(s);
                }
                __syncthreads();
            }
        }

        // ---- hierarchical device barrier (monotonic epoch) ----
        __syncthreads();
        if (tid == 0) {
            __threadfence();                 // release
            const unsigned target = (unsigned)(tick + 1);
            unsigned prev = atomicAdd(&leaf[(blk & 7) << 4], 1u);
            if (prev == 24u * target - 1u) { // last of this leaf
                prev = atomicAdd(root, 1u);
                if (prev == 8u * target - 1u)
                    __hip_atomic_store(epoch, target, __ATOMIC_RELEASE,
                                       __HIP_MEMORY_SCOPE_AGENT);
            }
            while (__hip_atomic_load(epoch, __ATOMIC_RELAXED,
                                     __HIP_MEMORY_SCOPE_AGENT) < target)
                __builtin_amdgcn_s_sleep(2);
            __threadfence();                 // acquire
        }
        __syncthreads();
    }

    // ---- LayerNorm over h = s_2(T-1) (slot 1), blocks 0..63, 2 elems/thread ----
    if (blk < BB) {
        const float* h = states + ((size_t)2 * 2 + 1) * SLAB + (size_t)blk * RSZ;
        float* red = &pbuf[0][0][0];

        const float hv0 = h[tid];
        const float hv1 = h[tid + 512];
        float v = hv0 + hv1;
#pragma unroll
        for (int o = 32; o > 0; o >>= 1) v += __shfl_down(v, o, 64);
        if ((tid & 63) == 0) red[tid >> 6] = v;
        __syncthreads();
        if (tid == 0) {
            float s = 0.f;
#pragma unroll
            for (int i = 0; i < 8; ++i) s += red[i];
            red[20] = s / (float)RSZ;
        }
        __syncthreads();
        const float mu = red[20];
        const float d0 = hv0 - mu, d1 = hv1 - mu;
        v = d0 * d0 + d1 * d1;
#pragma unroll
        for (int o = 32; o > 0; o >>= 1) v += __shfl_down(v, o, 64);
        __syncthreads();
        if ((tid & 63) == 0) red[tid >> 6] = v;
        __syncthreads();
        if (tid == 0) {
            float s = 0.f;
#pragma unroll
            for (int i = 0; i < 8; ++i) s += red[i];
            red[21] = rsqrtf(s / (float)RSZ + EPSLN);
        }
        __syncthreads();
        const float inv = red[21];
        out[blk * RSZ + tid]       = d0 * inv * ln_w[tid]       + ln_b[tid];
        out[blk * RSZ + tid + 512] = d1 * inv * ln_w[tid + 512] + ln_b[tid + 512];
    }
}

extern "C" void kernel_launch(void* const* d_in, const int* in_sizes, int n_in,
                              void* d_out, int out_size, void* d_ws, size_t ws_size,
                              hipStream_t stream) {
    const int*   x       = (const int*)  d_in[0];
    const float* embed_w = (const float*)d_in[1];
    const float* Win0    = (const float*)d_in[2];
    const float* Win1    = (const float*)d_in[3];
    const float* Win2    = (const float*)d_in[4];
    const float* Rm0     = (const float*)d_in[5];
    const float* Rm1     = (const float*)d_in[6];
    const float* Rm2     = (const float*)d_in[7];
    const float* ln_w    = (const float*)d_in[8];
    const float* ln_b    = (const float*)d_in[9];
    float*       out     = (float*)d_out;
    float*       states  = (float*)d_ws;
    unsigned*    bar     = (unsigned*)((float*)d_ws + BAR_OFF);

    hipMemsetAsync(d_ws, 0, (size_t)BAR_OFF * sizeof(float) + 4096, stream);

    void* args[] = {
        (void*)&x, (void*)&embed_w,
        (void*)&Win0, (void*)&Win1, (void*)&Win2,
        (void*)&Rm0, (void*)&Rm1, (void*)&Rm2,
        (void*)&ln_w, (void*)&ln_b,
        (void*)&states, (void*)&bar, (void*)&out
    };
    hipLaunchCooperativeKernel(reinterpret_cast<void*>(reservoir_main),
                               dim3(NBLK), dim3(NTHR), args, 0, stream);
}

// Round 14
// 68949.609 us; speedup vs baseline: 2.0815x; 1.3224x over previous
//
#include <hip/hip_runtime.h>

#define VV    32000
#define EE    256
#define RSZ   1024
#define BB    64
#define TT    2048
#define NGRP  3
#define EPSLN 1e-5f

#define NBLK_PER_GRP 64
#define NBLK  (NBLK_PER_GRP * NGRP)   // 192 blocks
#define NTHR  512                     // 8 waves = 16 k-groups x 32 threads
#define SLAB  (BB * RSZ)
#define NTICKS (TT + NGRP - 1)        // 2050

#define BAR_OFF (NGRP * 2 * SLAB)     // floats offset of barrier words in d_ws

// one k-step (4 k's): 8 rows x 4 cols = 128 FMAs per 4 weight ds_read_b128
__device__ __forceinline__ void fma_step8x4(const float4 (&b)[8], const float* wrow,
                                            float (&acc)[8][4]) {
#pragma unroll
    for (int j = 0; j < 4; ++j) {
        const float4 w = *reinterpret_cast<const float4*>(wrow + j * 16);
#pragma unroll
        for (int r = 0; r < 8; ++r) {
            const float a = reinterpret_cast<const float*>(&b[r])[j];
            acc[r][0] = fmaf(a, w.x, acc[r][0]);
            acc[r][1] = fmaf(a, w.y, acc[r][1]);
            acc[r][2] = fmaf(a, w.z, acc[r][2]);
            acc[r][3] = fmaf(a, w.w, acc[r][3]);
        }
    }
}

__device__ __forceinline__ void ld8(float4 (&b)[8], const float* const (&p)[8],
                                    int off) {
#pragma unroll
    for (int r = 0; r < 8; ++r)
        b[r] = *reinterpret_cast<const float4*>(p[r] + off);
}

// NSTEPS (even) k-steps; named A/B double-buffer, rolled 2-step loop (R10, verified)
template<int NSTEPS>
__device__ __forceinline__ void dot8(const float* const (&p)[8],
                                     const float* w, float (&acc)[8][4]) {
    float4 A[8], B[8];
    ld8(A, p, 0);
    ld8(B, p, 4);
    for (int j = 0; j < NSTEPS - 2; j += 2) {
        fma_step8x4(A, w + j * 64, acc);
        ld8(A, p, (j + 2) * 4);
        fma_step8x4(B, w + (j + 1) * 64, acc);
        ld8(B, p, (j + 3) * 4);
    }
    fma_step8x4(A, w + (NSTEPS - 2) * 64, acc);
    fma_step8x4(B, w + (NSTEPS - 1) * 64, acc);
}

__device__ __forceinline__ void wait_ge(unsigned* p, unsigned thr) {
    while (__hip_atomic_load(p, __ATOMIC_RELAXED, __HIP_MEMORY_SCOPE_AGENT) < thr)
        __builtin_amdgcn_s_sleep(2);
}

__global__ __launch_bounds__(NTHR, 1)
void reservoir_main(const int*   __restrict__ x,        // [B,T]
                    const float* __restrict__ embed_w,  // [V,E]
                    const float* __restrict__ Win0,
                    const float* __restrict__ Win1,
                    const float* __restrict__ Win2,
                    const float* __restrict__ Rm0,
                    const float* __restrict__ Rm1,
                    const float* __restrict__ Rm2,
                    const float* __restrict__ ln_w,
                    const float* __restrict__ ln_b,
                    float*       __restrict__ states,
                    unsigned*    __restrict__ bar,
                    float*       __restrict__ out)
{
    const int blk   = blockIdx.x;
    const int grp   = blk >> 6;              // layer
    const int gb    = blk & 63;
    const int c0    = gb << 4;               // 16-col slice
    const int tid   = threadIdx.x;
    const int kg    = tid >> 5;              // 0..15 (k-groups of 32 threads)
    const int idx   = tid & 31;
    const int rbase = (idx >> 2) << 3;       // 8 rows/thread: 0,8,...,56
    const int cg4   = (idx & 3) << 2;        // col quad
    const int lane  = tid & 63;
    const int g2    = tid >> 6;              // wave id = post-fold group 0..7

    const float* Wl  = (grp == 0) ? Win0 : ((grp == 1) ? Win1 : Win2);
    const float* Rl  = (grp == 0) ? Rm0  : ((grp == 1) ? Rm1  : Rm2);
    const int    Kw  = (grp == 0) ? EE : RSZ;
    const int    KwS = Kw >> 4;              // per-kg input k-slice (16 or 64)

    __shared__ float wlds[2048 * 16];        // 128 KB weight slab [k][16]
    __shared__ float pbuf[8][32][20];        // 20 KB partials (padded+swizzled)

    for (int i = tid; i < RSZ * 16; i += NTHR) {
        const int k = i >> 4, c = i & 15;
        wlds[i] = Rl[(size_t)k * RSZ + c0 + c];
    }
    for (int i = tid; i < Kw * 16; i += NTHR) {
        const int k = i >> 4, c = i & 15;
        wlds[RSZ * 16 + i] = Wl[(size_t)k * RSZ + c0 + c];
    }
    __syncthreads();

    // per-group barrier storage: group g at bar+g*256 (leaf i at +i*16, root +128, epoch +160)
    unsigned* gbar   = bar + grp * 256;
    unsigned* myleaf = gbar + ((gb & 7) << 4);
    unsigned* myroot = gbar + 128;
    unsigned* myep   = gbar + 160;
    unsigned* epP    = (grp > 0)         ? (bar + (grp - 1) * 256 + 160) : (unsigned*)0;
    unsigned* epC    = (grp < NGRP - 1)  ? (bar + (grp + 1) * 256 + 160) : (unsigned*)0;
    unsigned* ep2    = bar + 2 * 256 + 160;

    float* const sl = states + (size_t)grp * 2 * SLAB;
    const float* const wRb = wlds + (kg << 6) * 16 + cg4;            // R: k-slice 64
    const float* const wWb = wlds + (RSZ + kg * KwS) * 16 + cg4;

    int xidx[8];
    if (grp == 0) {
#pragma unroll
        for (int r = 0; r < 8; ++r) xidx[r] = x[(rbase + r) * TT + 0];
    }

    for (int tick = 0; tick < NTICKS; ++tick) {
        const int t = tick - grp;            // uniform per block
        if (0 <= t && t < TT) {
            const float* sprev = sl + (size_t)((t + 1) & 1) * SLAB;

            float acc[8][4];
#pragma unroll
            for (int r = 0; r < 8; ++r)
#pragma unroll
                for (int c = 0; c < 4; ++c) acc[r][c] = 0.f;

            {   // recurrent: s_prev @ R_l, k in [kg*64, kg*64+64) -> 16 ksteps
                const float* aR[8];
#pragma unroll
                for (int r = 0; r < 8; ++r)
                    aR[r] = sprev + (size_t)(rbase + r) * RSZ + (kg << 6);
                dot8<16>(aR, wRb, acc);
            }
            {   // input: cur @ W_l, k in [kg*KwS, +KwS) -> 4 or 16 ksteps
                const float* aW[8];
                if (grp == 0) {
#pragma unroll
                    for (int r = 0; r < 8; ++r)
                        aW[r] = embed_w + (size_t)xidx[r] * EE + kg * KwS;
                    dot8<4>(aW, wWb, acc);
                } else {
                    const float* cb = states + ((size_t)(grp - 1) * 2 + (t & 1)) * SLAB;
#pragma unroll
                    for (int r = 0; r < 8; ++r)
                        aW[r] = cb + (size_t)(rbase + r) * RSZ + kg * KwS;
                    dot8<16>(aW, wWb, acc);
                }
            }

            // prefetch next tick's token indices (layer 0 only)
            if (grp == 0 && t + 1 < TT) {
#pragma unroll
                for (int r = 0; r < 8; ++r) xidx[r] = x[(rbase + r) * TT + t + 1];
            }

            // ---- wave-level pre-reduce: fold kg pairs (16 -> 8 groups) ----
#pragma unroll
            for (int r = 0; r < 8; ++r)
#pragma unroll
                for (int c = 0; c < 4; ++c)
                    acc[r][c] += __shfl_down(acc[r][c], 32, 64);

            // ---- reduce over 8 groups, 2 row-half phases (R12, refchecked) ----
            float* sout = sl + (size_t)(t & 1) * SLAB;
#pragma unroll
            for (int p = 0; p < 2; ++p) {
                if (lane < 32 && (lane >> 4) == p) {
#pragma unroll
                    for (int r = 0; r < 8; ++r) {
                        const int lr = (rbase + r) & 31;
                        *reinterpret_cast<float4*>(
                            &pbuf[g2][lr][cg4 ^ ((lr & 3) << 2)])
                            = make_float4(acc[r][0], acc[r][1], acc[r][2], acc[r][3]);
                    }
                }
                __syncthreads();
                {
                    const int rl = tid >> 4, col = tid & 15;   // 512 thr = 32x16
                    const int cw = ((col & 12) ^ ((rl & 3) << 2)) | (col & 3);
                    float s = 0.f;
#pragma unroll
                    for (int g = 0; g < 8; ++g) s += pbuf[g][rl][cw];
                    sout[(size_t)(32 * p + rl) * RSZ + c0 + col] = tanhf(s);
                }
                __syncthreads();
            }
        }

        // ---- per-group barrier + neighbor-epoch waits (1-tick slack chain) ----
        __syncthreads();
        if (tid == 0) {
            __threadfence();                 // release own stores
            const unsigned target = (unsigned)(tick + 1);
            unsigned prev = atomicAdd(myleaf, 1u);
            if (prev == 8u * target - 1u) {  // last of this leaf (8 blocks)
                prev = atomicAdd(myroot, 1u);
                if (prev == 8u * target - 1u)  // last leaf (8 leaves)
                    __hip_atomic_store(myep, target, __ATOMIC_RELEASE,
                                       __HIP_MEMORY_SCOPE_AGENT);
            }
            wait_ge(myep, target);           // own group done tick
            if (epP) wait_ge(epP, target);   // producer done tick
            if (epC) wait_ge(epC, target);   // consumer done tick
            __threadfence();                 // acquire
        }
        __syncthreads();
    }

    // ---- LayerNorm over h = s_2(T-1) (slot 1), blocks 0..63, 2 elems/thread ----
    if (blk < BB) {
        if (tid == 0) {
            wait_ge(ep2, (unsigned)NTICKS);  // layer 2 fully done
            __threadfence();
        }
        __syncthreads();

        const float* h = states + ((size_t)2 * 2 + 1) * SLAB + (size_t)blk * RSZ;
        float* red = &pbuf[0][0][0];

        const float hv0 = h[tid];
        const float hv1 = h[tid + 512];
        float v = hv0 + hv1;
#pragma unroll
        for (int o = 32; o > 0; o >>= 1) v += __shfl_down(v, o, 64);
        if ((tid & 63) == 0) red[tid >> 6] = v;
        __syncthreads();
        if (tid == 0) {
            float s = 0.f;
#pragma unroll
            for (int i = 0; i < 8; ++i) s += red[i];
            red[20] = s / (float)RSZ;
        }
        __syncthreads();
        const float mu = red[20];
        const float d0 = hv0 - mu, d1 = hv1 - mu;
        v = d0 * d0 + d1 * d1;
#pragma unroll
        for (int o = 32; o > 0; o >>= 1) v += __shfl_down(v, o, 64);
        __syncthreads();
        if ((tid & 63) == 0) red[tid >> 6] = v;
        __syncthreads();
        if (tid == 0) {
            float s = 0.f;
#pragma unroll
            for (int i = 0; i < 8; ++i) s += red[i];
            red[21] = rsqrtf(s / (float)RSZ + EPSLN);
        }
        __syncthreads();
        const float inv = red[21];
        out[blk * RSZ + tid]       = d0 * inv * ln_w[tid]       + ln_b[tid];
        out[blk * RSZ + tid + 512] = d1 * inv * ln_w[tid + 512] + ln_b[tid + 512];
    }
}

extern "C" void kernel_launch(void* const* d_in, const int* in_sizes, int n_in,
                              void* d_out, int out_size, void* d_ws, size_t ws_size,
                              hipStream_t stream) {
    const int*   x       = (const int*)  d_in[0];
    const float* embed_w = (const float*)d_in[1];
    const float* Win0    = (const float*)d_in[2];
    const float* Win1    = (const float*)d_in[3];
    const float* Win2    = (const float*)d_in[4];
    const float* Rm0     = (const float*)d_in[5];
    const float* Rm1     = (const float*)d_in[6];
    const float* Rm2     = (const float*)d_in[7];
    const float* ln_w    = (const float*)d_in[8];
    const float* ln_b    = (const float*)d_in[9];
    float*       out     = (float*)d_out;
    float*       states  = (float*)d_ws;
    unsigned*    bar     = (unsigned*)((float*)d_ws + BAR_OFF);

    // zero states (s(-1)=0) AND all barrier counters; deterministic every call
    hipMemsetAsync(d_ws, 0, (size_t)BAR_OFF * sizeof(float) + 4096, stream);

    void* args[] = {
        (void*)&x, (void*)&embed_w,
        (void*)&Win0, (void*)&Win1, (void*)&Win2,
        (void*)&Rm0, (void*)&Rm1, (void*)&Rm2,
        (void*)&ln_w, (void*)&ln_b,
        (void*)&states, (void*)&bar, (void*)&out
    };
    hipLaunchCooperativeKernel(reinterpret_cast<void*>(reservoir_main),
                               dim3(NBLK), dim3(NTHR), args, 0, stream);
}